// Round 9
// baseline (167.060 us; speedup 1.0000x reference)
//
#include <hip/hip_runtime.h>
#include <hip/hip_bf16.h>
#include <type_traits>

// B=4, Y=64, X=64, C=256, H=8, F=32, 7x7 window (S=49). All I/O is FLOAT32.
// NOTE: measured dur_us includes ~55us of harness restore/re-poison
// (256MiB 0xAA fill at ~6TB/s) — kernel-side budget is dur_us - ~55.
static constexpr int NPOS = 4 * 64 * 64;   // 16384 rows
static constexpr int CD   = 256;
// r22: Vt row stride padded 16384 -> 16416 elem (32832B = 513 cache lines):
// exact-32KB stride put all 16 lrow lanes of a bv load in one L1 set.
static constexpr int VSTR = 16416;
#define QSCALE (0.17677669529663687f * 1.4426950408889634f)  // 1/sqrt(32)*log2e

typedef __attribute__((ext_vector_type(8))) short bf16x8;   // MFMA A/B frag
typedef __attribute__((ext_vector_type(4))) float f32x4;    // MFMA C/D frag

__device__ __forceinline__ float bf2f(unsigned short u) {
    return __uint_as_float((unsigned int)u << 16);
}
__device__ __forceinline__ unsigned short bfbits(float f) {
    union { __hip_bfloat16 h; unsigned short u; } cv;
    cv.h = __float2bfloat16(f);
    return cv.u;
}
__device__ __forceinline__ unsigned int packbf2(float lo, float hi) {
    union { __hip_bfloat162 h; unsigned int u; } cv;
    cv.h.x = __float2bfloat16(lo);
    cv.h.y = __float2bfloat16(hi);
    return cv.u;
}
__device__ __forceinline__ uint4 pack8(float4 a, float4 b) {
    uint4 u;
    u.x = packbf2(a.x, a.y); u.y = packbf2(a.z, a.w);
    u.z = packbf2(b.x, b.y); u.w = packbf2(b.z, b.w);
    return u;
}
// gfx950 cross-lane swaps via BUILTINS (VALU pipe; SSA pair results —
// immune to the tied-asm-operand coalescing that zeroed l in r19).
__device__ __forceinline__ void pl32swap(unsigned &a, unsigned &b) {
    auto r = __builtin_amdgcn_permlane32_swap(a, b, false, false);
    a = r[0]; b = r[1];
}
__device__ __forceinline__ void pl16swap(unsigned &a, unsigned &b) {
    auto r = __builtin_amdgcn_permlane16_swap(a, b, false, false);
    a = r[0]; b = r[1];
}

// ---------------------------------------------------------------------------
// convert: Wfrag (Wq|Wk|Wv b-frag bf16, 384KB) + pebf (pe^T b-frag,
// QSCALE-folded, 32KB) + Wofrag (128KB). 136 blocks x 256.  (unchanged)
// ---------------------------------------------------------------------------
__global__ __launch_bounds__(256) void convert_kernel(
    const float* __restrict__ Wq, const float* __restrict__ Wk,
    const float* __restrict__ Wv, const float* __restrict__ Wo,
    const float* __restrict__ pe,
    __hip_bfloat16* __restrict__ Wfrag,
    __hip_bfloat16* __restrict__ pebf,
    __hip_bfloat16* __restrict__ Wofrag)
{
    int t = blockIdx.x * 256 + threadIdx.x;
    if (t < 24576) {
        int L = t & 63, ng = (t >> 6) & 7, s = (t >> 9) & 7, T = t >> 12;
        int mat = T >> 1;
        const float* src = (mat == 0) ? Wq : (mat == 1) ? Wk : Wv;
        int ncol  = (T & 1) * 128 + ng * 16 + (L & 15);
        int kbase = s * 32 + (L >> 4) * 8;
        __hip_bfloat16* dst = Wfrag + ((size_t)((T * 8 + s) * 8 + ng) * 64 + L) * 8;
#pragma unroll
        for (int j = 0; j < 8; ++j)
            dst[j] = __float2bfloat16(src[(kbase + j) * 256 + ncol]);
    } else if (t < 26624) {
        int u = t - 24576;
        int L = u & 63, Tn = (u >> 6) & 3, h = u >> 8;
        int s = Tn * 16 + (L & 15);
        int kbase = (L >> 4) * 8;
        __hip_bfloat16* dst = pebf + ((size_t)((h * 4 + Tn) * 64 + L)) * 8;
#pragma unroll
        for (int j = 0; j < 8; ++j) {
            float v = (s < 49) ? pe[s * 256 + h * 32 + kbase + j] * QSCALE : 0.f;
            dst[j] = __float2bfloat16(v);
        }
    } else if (t < 34816) {
        int u = t - 26624;
        int L = u & 63, ng = (u >> 6) & 7, s = (u >> 9) & 7, T = (u >> 12) & 1;
        int ncol  = T * 128 + ng * 16 + (L & 15);
        int kbase = s * 32 + (L >> 4) * 8;
        __hip_bfloat16* dst = Wofrag + ((size_t)((T * 8 + s) * 8 + ng) * 64 + L) * 8;
#pragma unroll
        for (int j = 0; j < 8; ++j)
            dst[j] = __float2bfloat16(Wo[(kbase + j) * 256 + ncol]);
    }
}

// ---------------------------------------------------------------------------
// Kernel 1 (r21/r22): MERGED QKV GEMM — unchanged.
// ---------------------------------------------------------------------------
__global__ __launch_bounds__(768, 3) void qkv_mfma(
    const float* __restrict__ x,
    const __hip_bfloat16* __restrict__ Wfrag,
    const float* __restrict__ pe,
    unsigned short* __restrict__ QA,
    unsigned short* __restrict__ Kd,
    unsigned short* __restrict__ Vt)
{
    __shared__ __align__(16) unsigned short smem[256 * 68];   // 34.8 KB
    unsigned short* As = smem;                 // x-tile: [64][264] bf16
    const int t = threadIdx.x;                 // 0..767
    const int rowbase = blockIdx.x * 64;
    const int L = t & 63;
    const int w = t >> 6;                      // 0..11
    const int quad = L >> 4, lrow = L & 15;
    const int T = w >> 1;                      // 0..5
    const int ngb = (w & 1) * 4;
    const int g = T >> 1;                      // 0:Q 1:K 2:V
    const int lw = w & 3;                      // wave-within-g (col group)

#pragma unroll
    for (int idx = t; idx < 2048; idx += 768) {
        const int row = idx >> 5, ch8 = idx & 31;
        const float* src = x + (size_t)(rowbase + row) * CD + ch8 * 8;
        float4 f0 = ((const float4*)src)[0];
        float4 f1 = ((const float4*)src)[1];
        *(uint4*)&As[row * 264 + ch8 * 8] = pack8(f0, f1);
    }

    f32x4 acc[4][4];
#pragma unroll
    for (int i = 0; i < 4; ++i)
#pragma unroll
        for (int j = 0; j < 4; ++j) acc[i][j] = (f32x4){0.f, 0.f, 0.f, 0.f};

    const __hip_bfloat16* wbase = Wfrag + ((size_t)(T * 64 + ngb) * 64 + L) * 8;
    bf16x8 bfr[4];
#pragma unroll
    for (int j = 0; j < 4; ++j)
        bfr[j] = *(const bf16x8*)(wbase + (size_t)j * 64 * 8);

    __syncthreads();   // x-tile visible

#pragma unroll
    for (int s = 0; s < 8; ++s) {
        bf16x8 nbfr[4];
        if (s < 7) {
#pragma unroll
            for (int j = 0; j < 4; ++j)
                nbfr[j] = *(const bf16x8*)(wbase + (size_t)((s + 1) * 8 + j) * 64 * 8);
        }
#pragma unroll
        for (int i = 0; i < 4; ++i) {
            bf16x8 af = *(const bf16x8*)&As[(i * 16 + lrow) * 264 + s * 32 + quad * 8];
#pragma unroll
            for (int j = 0; j < 4; ++j)
                acc[i][j] = __builtin_amdgcn_mfma_f32_16x16x32_bf16(af, bfr[j], acc[i][j], 0, 0, 0);
        }
#pragma unroll
        for (int j = 0; j < 4; ++j) bfr[j] = nbfr[j];
    }

    __syncthreads();   // all x-tile reads done; smem may be reused by V

    if (g == 0) {
#pragma unroll
        for (int i = 0; i < 4; ++i)
#pragma unroll
            for (int r = 0; r < 4; ++r) {
                int row = rowbase + i * 16 + quad * 4 + r;
                int yy = (row >> 6) & 63, xx = row & 63;
                int cy = min(max(yy, 3), 60), cx = min(max(xx, 3), 60);
                int qidx = (yy - cy + 3) * 7 + (xx - cx + 3);
#pragma unroll
                for (int j = 0; j < 4; ++j) {
                    int c = lw * 64 + j * 16 + lrow;
                    QA[(size_t)row * CD + c] = bfbits(acc[i][j][r] + pe[qidx * 256 + c]);
                }
            }
    } else if (g == 1) {
#pragma unroll
        for (int i = 0; i < 4; ++i)
#pragma unroll
            for (int r = 0; r < 4; ++r) {
                int row = rowbase + i * 16 + quad * 4 + r;
#pragma unroll
                for (int j = 0; j < 4; ++j) {
                    int c = lw * 64 + j * 16 + lrow;
                    Kd[(size_t)row * CD + c] = bfbits(acc[i][j][r] * QSCALE);
                }
            }
    } else {
        unsigned short* vt = smem;   // [256 ch][68] bf16 (17408 shorts)
#pragma unroll
        for (int i = 0; i < 4; ++i)
#pragma unroll
            for (int j = 0; j < 4; ++j) {
                int c = lw * 64 + j * 16 + lrow;
                int row0 = i * 16 + quad * 4;
                *(unsigned int*)&vt[c * 68 + row0] =
                    (unsigned int)bfbits(acc[i][j][0]) | ((unsigned int)bfbits(acc[i][j][1]) << 16);
                *(unsigned int*)&vt[c * 68 + row0 + 2] =
                    (unsigned int)bfbits(acc[i][j][2]) | ((unsigned int)bfbits(acc[i][j][3]) << 16);
            }
    }
    __syncthreads();   // vt complete (uniform barrier — no barrier in branches)

    if (g == 2) {      // waves 8..11 (256 threads) stream vt -> Vt coalesced
        const int t4 = t - 512;
        const int grp = t4 >> 4, lig = t4 & 15;
        const int row_off = lig * 4;
        unsigned short* vt = smem;
#pragma unroll
        for (int pass = 0; pass < 16; ++pass) {
            int c = pass * 16 + grp;
            *(ushort4*)(Vt + (size_t)c * VSTR + rowbase + row_off) =
                *(const ushort4*)&vt[c * 68 + row_off];
        }
    }
}

// ---------------------------------------------------------------------------
// Kernel 2 (r26): r23 PAIRED-TILE attention + oproj, with DEPTH-2 PREFETCH
// and T5 setprio. r25's block-staging regressed (+4us: per-iter barriers +
// extra kernel) -> reverted to the r23 shape (best, 114.6). The residual
// stall theory: depth-1 prefetch covers only L2-hit latency (~200-400cy vs
// ~600cy compute); first-touch L3/HBM loads (~900cy) still stall. Depth-2
// (3 named register sets, loop fully unrolled for nit in {7,8} -> rotation
// is pure renaming, no scratch per rule #20) keeps 8 loads in flight =
// ~1200cy covered. setprio(1) around the MFMA/exp body: r23's loop is
// barrier-free so co-resident waves sit at different phases — the regime
// where setprio pays (attn +4-7%, m191). Numerics bit-identical to r23.
// ---------------------------------------------------------------------------
__global__ __launch_bounds__(512, 4) void attn_oproj(
    const unsigned short* __restrict__ QA,   // bf16 [pos][256] (Q + pe_q)
    const unsigned short* __restrict__ Kd,
    const unsigned short* __restrict__ Vt,
    const __hip_bfloat16* __restrict__ pebf,
    const __hip_bfloat16* __restrict__ Wofrag,
    float* __restrict__ out)
{
    __shared__ __align__(16) unsigned short qpes[8 * 2 * 1152];  // 36 KB
    __shared__ __align__(16) unsigned short At[2 * 16 * 264];    // 16.9 KB
    const int t = threadIdx.x, w = t >> 6, L = t & 63;
    const int lrow = L & 15, quad = L >> 4;
    const int bid = blockIdx.x;
    const int p = ((bid & 7) << 6) | (bid >> 3);   // XCD-local y-band
    const int b = p >> 7, ypair = (p >> 2) & 31, x0 = (p & 3) * 16;
    const int yyA = ypair * 2;
    const int pos0a = b * 4096 + yyA * 64 + x0;
    const int pos0b = pos0a + 64;
    const int cyA = min(max(yyA, 3), 60);
    const int cyB = min(max(yyA + 1, 3), 60);
    const int d = cyB - cyA;                  // 0 or 1
    const int h = w;

    const int kc0 = min(max(x0 - 8 + lrow, 0), 63);
    const int kc1 = min(max(x0 + 8 + lrow, 0), 63);
    const f32x4 zero = {0.f, 0.f, 0.f, 0.f};
    unsigned short* qpA = qpes + w * 2304;
    unsigned short* qpB = qpA + 1152;
    unsigned short* At_a = At;
    unsigned short* At_b = At + 16 * 264;

    // x-geometry (shared by both tiles)
    const int cx = min(max(x0 + lrow, 3), 60) - x0 + 5;
    int qiA[4], qiB[4];
    float mkA[4], mkB[4];
#pragma unroll
    for (int r = 0; r < 4; ++r) {
        const int sl = quad * 4 + r;
        int dxa = sl - cx;
        qiA[r] = lrow * 72 + min(max(dxa, 0), 6);
        mkA[r] = ((unsigned)dxa <= 6u) ? 1.f : 0.f;
        int dxb = 16 + sl - cx;
        qiB[r] = lrow * 72 + min(max(dxb, 0), 6);
        mkB[r] = ((unsigned)dxb <= 6u) ? 1.f : 0.f;
    }

    const bf16x8 qaA = *(const bf16x8*)(QA + (size_t)(pos0a + lrow) * 256 + h * 32 + quad * 8);
    const bf16x8 qaB = *(const bf16x8*)(QA + (size_t)(pos0b + lrow) * 256 + h * 32 + quad * 8);

    // QpeT for both tiles (pe b-frag loaded once per Tn)
#pragma unroll
    for (int Tn = 0; Tn < 4; ++Tn) {
        bf16x8 bp = *(const bf16x8*)(pebf + ((size_t)((h * 4 + Tn) * 64 + L)) * 8);
        f32x4 cA = __builtin_amdgcn_mfma_f32_16x16x32_bf16(bp, qaA, zero, 0, 0, 0);
        f32x4 cB = __builtin_amdgcn_mfma_f32_16x16x32_bf16(bp, qaB, zero, 0, 0, 0);
        *(unsigned int*)&qpA[lrow * 72 + Tn * 16 + quad * 4]     = packbf2(cA[0], cA[1]);
        *(unsigned int*)&qpA[lrow * 72 + Tn * 16 + quad * 4 + 2] = packbf2(cA[2], cA[3]);
        *(unsigned int*)&qpB[lrow * 72 + Tn * 16 + quad * 4]     = packbf2(cB[0], cB[1]);
        *(unsigned int*)&qpB[lrow * 72 + Tn * 16 + quad * 4 + 2] = packbf2(cB[2], cB[3]);
    }
    __builtin_amdgcn_s_waitcnt(0xc07f);   // lgkmcnt(0): qp visible to own wave

    float laccA = 0.f, laccB = 0.f;
    f32x4 o0a = zero, o1a = zero, o0b = zero, o1b = zero;
    const int row0 = b * 4096 + (cyA - 3) * 64;

    const size_t koff = h * 32 + quad * 8;
    const size_t voff0 = (size_t)(h * 32 + lrow) * VSTR + x0 - 8 + quad * 8;
    const size_t voff1 = (size_t)(h * 32 + 16 + lrow) * VSTR + x0 - 8 + quad * 8;

    // current / +1 / +2 register sets (named: full unroll renames, no moves)
    bf16x8 ck0, ck1, cv0, cv1, pk0, pk1, pv0, pv1;
    ck0 = *(const bf16x8*)(Kd + (size_t)(row0 + kc0) * 256 + koff);
    ck1 = *(const bf16x8*)(Kd + (size_t)(row0 + kc1) * 256 + koff);
    cv0 = *(const bf16x8*)(Vt + voff0 + row0);
    cv1 = *(const bf16x8*)(Vt + voff1 + row0);
    pk0 = *(const bf16x8*)(Kd + (size_t)(row0 + 64 + kc0) * 256 + koff);
    pk1 = *(const bf16x8*)(Kd + (size_t)(row0 + 64 + kc1) * 256 + koff);
    pv0 = *(const bf16x8*)(Vt + voff0 + row0 + 64);
    pv1 = *(const bf16x8*)(Vt + voff1 + row0 + 64);

    auto tilestep = [&](const bf16x8& qa_, const unsigned short* qp_, int qpofs,
                        float& lacc_, f32x4& o0_, f32x4& o1_) {
        f32x4 s0 = __builtin_amdgcn_mfma_f32_16x16x32_bf16(ck0, qa_, zero, 0, 0, 0);
        f32x4 s1 = __builtin_amdgcn_mfma_f32_16x16x32_bf16(ck1, qa_, zero, 0, 0, 0);
        float e00 = exp2f(s0[0] + bf2f(qp_[qiA[0] + qpofs])) * mkA[0];
        float e01 = exp2f(s0[1] + bf2f(qp_[qiA[1] + qpofs])) * mkA[1];
        float e02 = exp2f(s0[2] + bf2f(qp_[qiA[2] + qpofs])) * mkA[2];
        float e03 = exp2f(s0[3] + bf2f(qp_[qiA[3] + qpofs])) * mkA[3];
        float e10 = exp2f(s1[0] + bf2f(qp_[qiB[0] + qpofs])) * mkB[0];
        float e11 = exp2f(s1[1] + bf2f(qp_[qiB[1] + qpofs])) * mkB[1];
        float e12 = exp2f(s1[2] + bf2f(qp_[qiB[2] + qpofs])) * mkB[2];
        float e13 = exp2f(s1[3] + bf2f(qp_[qiB[3] + qpofs])) * mkB[3];
        lacc_ += ((e00 + e01) + (e02 + e03)) + ((e10 + e11) + (e12 + e13));
        unsigned p0 = packbf2(e00, e01), p1 = packbf2(e02, e03);
        unsigned z0 = packbf2(e10, e11), z1 = packbf2(e12, e13);
        pl32swap(p0, z0); pl16swap(p0, z0);
        pl32swap(p1, z1); pl16swap(p1, z1);
        union { unsigned u[4]; bf16x8 v; } pb;
        pb.u[0] = p0; pb.u[1] = p1; pb.u[2] = z0; pb.u[3] = z1;
        o0_ = __builtin_amdgcn_mfma_f32_16x16x32_bf16(cv0, pb.v, o0_, 0, 0, 0);
        o1_ = __builtin_amdgcn_mfma_f32_16x16x32_bf16(cv1, pb.v, o1_, 0, 0, 0);
    };

    auto runloop = [&](auto NITC) {
        constexpr int NIT = NITC.value;
        constexpr int D = NIT - 7;
#pragma unroll
        for (int it = 0; it < NIT; ++it) {
            bf16x8 qk0, qk1, qv0, qv1;              // it+2 loads in flight
            if (it + 2 < NIT) {
                const int rpf = row0 + (it + 2) * 64;
                qk0 = *(const bf16x8*)(Kd + (size_t)(rpf + kc0) * 256 + koff);
                qk1 = *(const bf16x8*)(Kd + (size_t)(rpf + kc1) * 256 + koff);
                qv0 = *(const bf16x8*)(Vt + voff0 + rpf);
                qv1 = *(const bf16x8*)(Vt + voff1 + rpf);
            }
            __builtin_amdgcn_s_setprio(1);
            if (it < 7)
                tilestep(qaA, qpA, it * 7, laccA, o0a, o1a);
            if (it >= D)
                tilestep(qaB, qpB, (it - D) * 7, laccB, o0b, o1b);
            __builtin_amdgcn_s_setprio(0);
            ck0 = pk0; ck1 = pk1; cv0 = pv0; cv1 = pv1;
            pk0 = qk0; pk1 = qk1; pv0 = qv0; pv1 = qv1;
        }
    };
    if (d == 0) runloop(std::integral_constant<int, 7>{});
    else        runloop(std::integral_constant<int, 8>{});

    // l-reduce across the 4 quads; write normalized O^T into At (both tiles)
    laccA += __shfl_xor(laccA, 16);
    laccA += __shfl_xor(laccA, 32);
    laccB += __shfl_xor(laccB, 16);
    laccB += __shfl_xor(laccB, 32);
    const float invA = 1.f / (laccA + 1e-8f);
    const float invB = 1.f / (laccB + 1e-8f);
    {
        const int base = lrow * 264 + h * 32 + quad * 4;
        *(unsigned int*)&At_a[base]          = packbf2(o0a[0] * invA, o0a[1] * invA);
        *(unsigned int*)&At_a[base + 2]      = packbf2(o0a[2] * invA, o0a[3] * invA);
        *(unsigned int*)&At_a[base + 16]     = packbf2(o1a[0] * invA, o1a[1] * invA);
        *(unsigned int*)&At_a[base + 16 + 2] = packbf2(o1a[2] * invA, o1a[3] * invA);
        *(unsigned int*)&At_b[base]          = packbf2(o0b[0] * invB, o0b[1] * invB);
        *(unsigned int*)&At_b[base + 2]      = packbf2(o0b[2] * invB, o0b[3] * invB);
        *(unsigned int*)&At_b[base + 16]     = packbf2(o1b[0] * invB, o1b[1] * invB);
        *(unsigned int*)&At_b[base + 16 + 2] = packbf2(o1b[2] * invB, o1b[3] * invB);
    }
    __syncthreads();

    // ---- oproj: both tiles share each Wofrag fragment ---------------------
    const int T = w >> 2;
    const int ngb = (w & 3) * 2;
    f32x4 accA[2], accB[2];
    accA[0] = zero; accA[1] = zero; accB[0] = zero; accB[1] = zero;

#pragma unroll
    for (int s = 0; s < 8; ++s) {
        bf16x8 bfr[2];
#pragma unroll
        for (int j = 0; j < 2; ++j)
            bfr[j] = *(const bf16x8*)(Wofrag +
                      ((size_t)((T * 8 + s) * 8 + ngb + j) * 64 + L) * 8);
        bf16x8 afA = *(const bf16x8*)(At_a + lrow * 264 + s * 32 + quad * 8);
        bf16x8 afB = *(const bf16x8*)(At_b + lrow * 264 + s * 32 + quad * 8);
#pragma unroll
        for (int j = 0; j < 2; ++j) {
            accA[j] = __builtin_amdgcn_mfma_f32_16x16x32_bf16(afA, bfr[j], accA[j], 0, 0, 0);
            accB[j] = __builtin_amdgcn_mfma_f32_16x16x32_bf16(afB, bfr[j], accB[j], 0, 0, 0);
        }
    }

#pragma unroll
    for (int r = 0; r < 4; ++r) {
        int rowA = pos0a + quad * 4 + r;
        int rowB = pos0b + quad * 4 + r;
#pragma unroll
        for (int j = 0; j < 2; ++j) {
            int c = w * 32 + j * 16 + lrow;
            out[(size_t)rowA * CD + c] = accA[j][r];
            out[(size_t)rowB * CD + c] = accB[j][r];
        }
    }
}

// ---------------------------------------------------------------------------
// Memory plan (ws ~256 MiB; we use ~26 MB):
//   ws[ 0,  8MB): QA bf16 (Q + pe_q)
//   ws[ 8, 16MB): Kd bf16 (QSCALE-folded; tail absorbs Vt underflow reads)
//   ws[16, ~24.02MB): Vt bf16 transposed [ch][VSTR=16416] (8.02 MB)
//   ws[25MB+4KB, +544KB): Wfrag 384KB | pebf 32KB | Wofrag 128KB
// ---------------------------------------------------------------------------
extern "C" void kernel_launch(void* const* d_in, const int* in_sizes, int n_in,
                              void* d_out, int out_size, void* d_ws, size_t ws_size,
                              hipStream_t stream)
{
    const float* x  = (const float*)d_in[0];
    const float* Wq = (const float*)d_in[1];
    const float* Wk = (const float*)d_in[2];
    const float* Wv = (const float*)d_in[3];
    const float* Wo = (const float*)d_in[4];
    const float* pe = (const float*)d_in[5];
    float* out = (float*)d_out;

    char* ws = (char*)d_ws;
    unsigned short* QA = (unsigned short*)ws;
    unsigned short* Kd = (unsigned short*)(ws + (8u << 20));
    unsigned short* Vt = (unsigned short*)(ws + (16u << 20));
    char* fr = ws + (25u << 20) + 4096;
    __hip_bfloat16* Wfrag  = (__hip_bfloat16*)fr;
    __hip_bfloat16* pebf   = (__hip_bfloat16*)(fr + (384u << 10));
    __hip_bfloat16* Wofrag = (__hip_bfloat16*)(fr + (416u << 10));

    convert_kernel<<<136, 256, 0, stream>>>(Wq, Wk, Wv, Wo, pe, Wfrag, pebf, Wofrag);
    qkv_mfma<<<256, 768, 0, stream>>>(x, Wfrag, pe, QA, Kd, Vt);
    attn_oproj<<<512, 512, 0, stream>>>(QA, Kd, Vt, pebf, Wofrag, out);
}

// Round 10
// 118.358 us; speedup vs baseline: 1.4115x; 1.4115x over previous
//
#include <hip/hip_runtime.h>
#include <hip/hip_bf16.h>

// B=4, Y=64, X=64, C=256, H=8, F=32, 7x7 window (S=49). All I/O is FLOAT32.
// NOTE: measured dur_us includes ~55us of harness restore/re-poison
// (256MiB 0xAA fill at ~6TB/s) — kernel-side budget is dur_us - ~55.
static constexpr int NPOS = 4 * 64 * 64;   // 16384 rows
static constexpr int CD   = 256;
// r22: Vt row stride padded 16384 -> 16416 elem (32832B = 513 cache lines):
// exact-32KB stride put all 16 lrow lanes of a bv load in one L1 set.
static constexpr int VSTR = 16416;
#define QSCALE (0.17677669529663687f * 1.4426950408889634f)  // 1/sqrt(32)*log2e

typedef __attribute__((ext_vector_type(8))) short bf16x8;   // MFMA A/B frag
typedef __attribute__((ext_vector_type(4))) float f32x4;    // MFMA C/D frag

__device__ __forceinline__ float bf2f(unsigned short u) {
    return __uint_as_float((unsigned int)u << 16);
}
__device__ __forceinline__ unsigned short bfbits(float f) {
    union { __hip_bfloat16 h; unsigned short u; } cv;
    cv.h = __float2bfloat16(f);
    return cv.u;
}
__device__ __forceinline__ unsigned int packbf2(float lo, float hi) {
    union { __hip_bfloat162 h; unsigned int u; } cv;
    cv.h.x = __float2bfloat16(lo);
    cv.h.y = __float2bfloat16(hi);
    return cv.u;
}
__device__ __forceinline__ uint4 pack8(float4 a, float4 b) {
    uint4 u;
    u.x = packbf2(a.x, a.y); u.y = packbf2(a.z, a.w);
    u.z = packbf2(b.x, b.y); u.w = packbf2(b.z, b.w);
    return u;
}
// gfx950 cross-lane swaps via BUILTINS (VALU pipe; SSA pair results —
// immune to the tied-asm-operand coalescing that zeroed l in r19).
__device__ __forceinline__ void pl32swap(unsigned &a, unsigned &b) {
    auto r = __builtin_amdgcn_permlane32_swap(a, b, false, false);
    a = r[0]; b = r[1];
}
__device__ __forceinline__ void pl16swap(unsigned &a, unsigned &b) {
    auto r = __builtin_amdgcn_permlane16_swap(a, b, false, false);
    a = r[0]; b = r[1];
}

// ---------------------------------------------------------------------------
// convert: Wfrag (Wq|Wk|Wv b-frag bf16, 384KB) + pebf (pe^T b-frag,
// QSCALE-folded, 32KB) + Wofrag (128KB). 136 blocks x 256.  (unchanged)
// ---------------------------------------------------------------------------
__global__ __launch_bounds__(256) void convert_kernel(
    const float* __restrict__ Wq, const float* __restrict__ Wk,
    const float* __restrict__ Wv, const float* __restrict__ Wo,
    const float* __restrict__ pe,
    __hip_bfloat16* __restrict__ Wfrag,
    __hip_bfloat16* __restrict__ pebf,
    __hip_bfloat16* __restrict__ Wofrag)
{
    int t = blockIdx.x * 256 + threadIdx.x;
    if (t < 24576) {
        int L = t & 63, ng = (t >> 6) & 7, s = (t >> 9) & 7, T = t >> 12;
        int mat = T >> 1;
        const float* src = (mat == 0) ? Wq : (mat == 1) ? Wk : Wv;
        int ncol  = (T & 1) * 128 + ng * 16 + (L & 15);
        int kbase = s * 32 + (L >> 4) * 8;
        __hip_bfloat16* dst = Wfrag + ((size_t)((T * 8 + s) * 8 + ng) * 64 + L) * 8;
#pragma unroll
        for (int j = 0; j < 8; ++j)
            dst[j] = __float2bfloat16(src[(kbase + j) * 256 + ncol]);
    } else if (t < 26624) {
        int u = t - 24576;
        int L = u & 63, Tn = (u >> 6) & 3, h = u >> 8;
        int s = Tn * 16 + (L & 15);
        int kbase = (L >> 4) * 8;
        __hip_bfloat16* dst = pebf + ((size_t)((h * 4 + Tn) * 64 + L)) * 8;
#pragma unroll
        for (int j = 0; j < 8; ++j) {
            float v = (s < 49) ? pe[s * 256 + h * 32 + kbase + j] * QSCALE : 0.f;
            dst[j] = __float2bfloat16(v);
        }
    } else if (t < 34816) {
        int u = t - 26624;
        int L = u & 63, ng = (u >> 6) & 7, s = (u >> 9) & 7, T = (u >> 12) & 1;
        int ncol  = T * 128 + ng * 16 + (L & 15);
        int kbase = s * 32 + (L >> 4) * 8;
        __hip_bfloat16* dst = Wofrag + ((size_t)((T * 8 + s) * 8 + ng) * 64 + L) * 8;
#pragma unroll
        for (int j = 0; j < 8; ++j)
            dst[j] = __float2bfloat16(Wo[(kbase + j) * 256 + ncol]);
    }
}

// ---------------------------------------------------------------------------
// Kernel 1 (r21/r22): MERGED QKV GEMM — unchanged.
// ---------------------------------------------------------------------------
__global__ __launch_bounds__(768, 3) void qkv_mfma(
    const float* __restrict__ x,
    const __hip_bfloat16* __restrict__ Wfrag,
    const float* __restrict__ pe,
    unsigned short* __restrict__ QA,
    unsigned short* __restrict__ Kd,
    unsigned short* __restrict__ Vt)
{
    __shared__ __align__(16) unsigned short smem[256 * 68];   // 34.8 KB
    unsigned short* As = smem;                 // x-tile: [64][264] bf16
    const int t = threadIdx.x;                 // 0..767
    const int rowbase = blockIdx.x * 64;
    const int L = t & 63;
    const int w = t >> 6;                      // 0..11
    const int quad = L >> 4, lrow = L & 15;
    const int T = w >> 1;                      // 0..5
    const int ngb = (w & 1) * 4;
    const int g = T >> 1;                      // 0:Q 1:K 2:V
    const int lw = w & 3;                      // wave-within-g (col group)

#pragma unroll
    for (int idx = t; idx < 2048; idx += 768) {
        const int row = idx >> 5, ch8 = idx & 31;
        const float* src = x + (size_t)(rowbase + row) * CD + ch8 * 8;
        float4 f0 = ((const float4*)src)[0];
        float4 f1 = ((const float4*)src)[1];
        *(uint4*)&As[row * 264 + ch8 * 8] = pack8(f0, f1);
    }

    f32x4 acc[4][4];
#pragma unroll
    for (int i = 0; i < 4; ++i)
#pragma unroll
        for (int j = 0; j < 4; ++j) acc[i][j] = (f32x4){0.f, 0.f, 0.f, 0.f};

    const __hip_bfloat16* wbase = Wfrag + ((size_t)(T * 64 + ngb) * 64 + L) * 8;
    bf16x8 bfr[4];
#pragma unroll
    for (int j = 0; j < 4; ++j)
        bfr[j] = *(const bf16x8*)(wbase + (size_t)j * 64 * 8);

    __syncthreads();   // x-tile visible

#pragma unroll
    for (int s = 0; s < 8; ++s) {
        bf16x8 nbfr[4];
        if (s < 7) {
#pragma unroll
            for (int j = 0; j < 4; ++j)
                nbfr[j] = *(const bf16x8*)(wbase + (size_t)((s + 1) * 8 + j) * 64 * 8);
        }
#pragma unroll
        for (int i = 0; i < 4; ++i) {
            bf16x8 af = *(const bf16x8*)&As[(i * 16 + lrow) * 264 + s * 32 + quad * 8];
#pragma unroll
            for (int j = 0; j < 4; ++j)
                acc[i][j] = __builtin_amdgcn_mfma_f32_16x16x32_bf16(af, bfr[j], acc[i][j], 0, 0, 0);
        }
#pragma unroll
        for (int j = 0; j < 4; ++j) bfr[j] = nbfr[j];
    }

    __syncthreads();   // all x-tile reads done; smem may be reused by V

    if (g == 0) {
#pragma unroll
        for (int i = 0; i < 4; ++i)
#pragma unroll
            for (int r = 0; r < 4; ++r) {
                int row = rowbase + i * 16 + quad * 4 + r;
                int yy = (row >> 6) & 63, xx = row & 63;
                int cy = min(max(yy, 3), 60), cx = min(max(xx, 3), 60);
                int qidx = (yy - cy + 3) * 7 + (xx - cx + 3);
#pragma unroll
                for (int j = 0; j < 4; ++j) {
                    int c = lw * 64 + j * 16 + lrow;
                    QA[(size_t)row * CD + c] = bfbits(acc[i][j][r] + pe[qidx * 256 + c]);
                }
            }
    } else if (g == 1) {
#pragma unroll
        for (int i = 0; i < 4; ++i)
#pragma unroll
            for (int r = 0; r < 4; ++r) {
                int row = rowbase + i * 16 + quad * 4 + r;
#pragma unroll
                for (int j = 0; j < 4; ++j) {
                    int c = lw * 64 + j * 16 + lrow;
                    Kd[(size_t)row * CD + c] = bfbits(acc[i][j][r] * QSCALE);
                }
            }
    } else {
        unsigned short* vt = smem;   // [256 ch][68] bf16 (17408 shorts)
#pragma unroll
        for (int i = 0; i < 4; ++i)
#pragma unroll
            for (int j = 0; j < 4; ++j) {
                int c = lw * 64 + j * 16 + lrow;
                int row0 = i * 16 + quad * 4;
                *(unsigned int*)&vt[c * 68 + row0] =
                    (unsigned int)bfbits(acc[i][j][0]) | ((unsigned int)bfbits(acc[i][j][1]) << 16);
                *(unsigned int*)&vt[c * 68 + row0 + 2] =
                    (unsigned int)bfbits(acc[i][j][2]) | ((unsigned int)bfbits(acc[i][j][3]) << 16);
            }
    }
    __syncthreads();   // vt complete (uniform barrier — no barrier in branches)

    if (g == 2) {      // waves 8..11 (256 threads) stream vt -> Vt coalesced
        const int t4 = t - 512;
        const int grp = t4 >> 4, lig = t4 & 15;
        const int row_off = lig * 4;
        unsigned short* vt = smem;
#pragma unroll
        for (int pass = 0; pass < 16; ++pass) {
            int c = pass * 16 + grp;
            *(ushort4*)(Vt + (size_t)c * VSTR + rowbase + row_off) =
                *(const ushort4*)&vt[c * 68 + row_off];
        }
    }
}

// ---------------------------------------------------------------------------
// Kernel 2 (r27): r23 PAIRED-TILE attention + oproj with DEPTH-2 PREFETCH,
// PROPERLY RESOURCED. r26's version of this died on a self-inflicted
// 64-VGPR cap: __launch_bounds__(512,4) pinned 8 waves/SIMD, the depth-2
// pipeline (~100 VGPR) spilled to scratch -> 110MB FETCH / 198MB WRITE of
// spill traffic, attn 90us. Fix: __launch_bounds__(512) (no clamp), dynamic
// loop (no mega-unroll), no setprio. Expected ~110 VGPR -> 16 waves/CU
// (vs r23's 24) but 8 loads in flight (~1200cy covered >= worst-case ~900cy
// L3/HBM first-touch) vs depth-1's ~400cy. Numerics bit-identical to r23.
// ---------------------------------------------------------------------------
__global__ __launch_bounds__(512) void attn_oproj(
    const unsigned short* __restrict__ QA,   // bf16 [pos][256] (Q + pe_q)
    const unsigned short* __restrict__ Kd,
    const unsigned short* __restrict__ Vt,
    const __hip_bfloat16* __restrict__ pebf,
    const __hip_bfloat16* __restrict__ Wofrag,
    float* __restrict__ out)
{
    __shared__ __align__(16) unsigned short qpes[8 * 2 * 1152];  // 36 KB
    __shared__ __align__(16) unsigned short At[2 * 16 * 264];    // 16.9 KB
    const int t = threadIdx.x, w = t >> 6, L = t & 63;
    const int lrow = L & 15, quad = L >> 4;
    const int bid = blockIdx.x;
    const int p = ((bid & 7) << 6) | (bid >> 3);   // XCD-local y-band
    const int b = p >> 7, ypair = (p >> 2) & 31, x0 = (p & 3) * 16;
    const int yyA = ypair * 2;
    const int pos0a = b * 4096 + yyA * 64 + x0;
    const int pos0b = pos0a + 64;
    const int cyA = min(max(yyA, 3), 60);
    const int cyB = min(max(yyA + 1, 3), 60);
    const int d = cyB - cyA;                  // 0 or 1
    const int nit = 7 + d;                    // 7 or 8 shared K/V rows
    const int h = w;

    const int kc0 = min(max(x0 - 8 + lrow, 0), 63);
    const int kc1 = min(max(x0 + 8 + lrow, 0), 63);
    const f32x4 zero = {0.f, 0.f, 0.f, 0.f};
    unsigned short* qpA = qpes + w * 2304;
    unsigned short* qpB = qpA + 1152;
    unsigned short* At_a = At;
    unsigned short* At_b = At + 16 * 264;

    // x-geometry (shared by both tiles)
    const int cx = min(max(x0 + lrow, 3), 60) - x0 + 5;
    int qiA[4], qiB[4];
    float mkA[4], mkB[4];
#pragma unroll
    for (int r = 0; r < 4; ++r) {
        const int sl = quad * 4 + r;
        int dxa = sl - cx;
        qiA[r] = lrow * 72 + min(max(dxa, 0), 6);
        mkA[r] = ((unsigned)dxa <= 6u) ? 1.f : 0.f;
        int dxb = 16 + sl - cx;
        qiB[r] = lrow * 72 + min(max(dxb, 0), 6);
        mkB[r] = ((unsigned)dxb <= 6u) ? 1.f : 0.f;
    }

    const bf16x8 qaA = *(const bf16x8*)(QA + (size_t)(pos0a + lrow) * 256 + h * 32 + quad * 8);
    const bf16x8 qaB = *(const bf16x8*)(QA + (size_t)(pos0b + lrow) * 256 + h * 32 + quad * 8);

    // QpeT for both tiles (pe b-frag loaded once per Tn)
#pragma unroll
    for (int Tn = 0; Tn < 4; ++Tn) {
        bf16x8 bp = *(const bf16x8*)(pebf + ((size_t)((h * 4 + Tn) * 64 + L)) * 8);
        f32x4 cA = __builtin_amdgcn_mfma_f32_16x16x32_bf16(bp, qaA, zero, 0, 0, 0);
        f32x4 cB = __builtin_amdgcn_mfma_f32_16x16x32_bf16(bp, qaB, zero, 0, 0, 0);
        *(unsigned int*)&qpA[lrow * 72 + Tn * 16 + quad * 4]     = packbf2(cA[0], cA[1]);
        *(unsigned int*)&qpA[lrow * 72 + Tn * 16 + quad * 4 + 2] = packbf2(cA[2], cA[3]);
        *(unsigned int*)&qpB[lrow * 72 + Tn * 16 + quad * 4]     = packbf2(cB[0], cB[1]);
        *(unsigned int*)&qpB[lrow * 72 + Tn * 16 + quad * 4 + 2] = packbf2(cB[2], cB[3]);
    }
    __builtin_amdgcn_s_waitcnt(0xc07f);   // lgkmcnt(0): qp visible to own wave

    float laccA = 0.f, laccB = 0.f;
    f32x4 o0a = zero, o1a = zero, o0b = zero, o1b = zero;
    const int row0 = b * 4096 + (cyA - 3) * 64;

    const size_t koff = h * 32 + quad * 8;
    const size_t voff0 = (size_t)(h * 32 + lrow) * VSTR + x0 - 8 + quad * 8;
    const size_t voff1 = (size_t)(h * 32 + 16 + lrow) * VSTR + x0 - 8 + quad * 8;

    // depth-2 register pipeline: ck* = row it, pk* = row it+1; qk* = it+2.
    bf16x8 ck0, ck1, cv0, cv1, pk0, pk1, pv0, pv1;
    ck0 = *(const bf16x8*)(Kd + (size_t)(row0 + kc0) * 256 + koff);
    ck1 = *(const bf16x8*)(Kd + (size_t)(row0 + kc1) * 256 + koff);
    cv0 = *(const bf16x8*)(Vt + voff0 + row0);
    cv1 = *(const bf16x8*)(Vt + voff1 + row0);
    pk0 = *(const bf16x8*)(Kd + (size_t)(row0 + 64 + kc0) * 256 + koff);
    pk1 = *(const bf16x8*)(Kd + (size_t)(row0 + 64 + kc1) * 256 + koff);
    pv0 = *(const bf16x8*)(Vt + voff0 + row0 + 64);
    pv1 = *(const bf16x8*)(Vt + voff1 + row0 + 64);

    auto tilestep = [&](const bf16x8& qa_, const unsigned short* qp_, int qpofs,
                        float& lacc_, f32x4& o0_, f32x4& o1_) {
        f32x4 s0 = __builtin_amdgcn_mfma_f32_16x16x32_bf16(ck0, qa_, zero, 0, 0, 0);
        f32x4 s1 = __builtin_amdgcn_mfma_f32_16x16x32_bf16(ck1, qa_, zero, 0, 0, 0);
        float e00 = exp2f(s0[0] + bf2f(qp_[qiA[0] + qpofs])) * mkA[0];
        float e01 = exp2f(s0[1] + bf2f(qp_[qiA[1] + qpofs])) * mkA[1];
        float e02 = exp2f(s0[2] + bf2f(qp_[qiA[2] + qpofs])) * mkA[2];
        float e03 = exp2f(s0[3] + bf2f(qp_[qiA[3] + qpofs])) * mkA[3];
        float e10 = exp2f(s1[0] + bf2f(qp_[qiB[0] + qpofs])) * mkB[0];
        float e11 = exp2f(s1[1] + bf2f(qp_[qiB[1] + qpofs])) * mkB[1];
        float e12 = exp2f(s1[2] + bf2f(qp_[qiB[2] + qpofs])) * mkB[2];
        float e13 = exp2f(s1[3] + bf2f(qp_[qiB[3] + qpofs])) * mkB[3];
        lacc_ += ((e00 + e01) + (e02 + e03)) + ((e10 + e11) + (e12 + e13));
        unsigned p0 = packbf2(e00, e01), p1 = packbf2(e02, e03);
        unsigned z0 = packbf2(e10, e11), z1 = packbf2(e12, e13);
        pl32swap(p0, z0); pl16swap(p0, z0);
        pl32swap(p1, z1); pl16swap(p1, z1);
        union { unsigned u[4]; bf16x8 v; } pb;
        pb.u[0] = p0; pb.u[1] = p1; pb.u[2] = z0; pb.u[3] = z1;
        o0_ = __builtin_amdgcn_mfma_f32_16x16x32_bf16(cv0, pb.v, o0_, 0, 0, 0);
        o1_ = __builtin_amdgcn_mfma_f32_16x16x32_bf16(cv1, pb.v, o1_, 0, 0, 0);
    };

    for (int it = 0; it < nit; ++it) {
        bf16x8 qk0, qk1, qv0, qv1;             // row it+2 loads in flight
        if (it + 2 < nit) {
            const int rpf = row0 + (it + 2) * 64;
            qk0 = *(const bf16x8*)(Kd + (size_t)(rpf + kc0) * 256 + koff);
            qk1 = *(const bf16x8*)(Kd + (size_t)(rpf + kc1) * 256 + koff);
            qv0 = *(const bf16x8*)(Vt + voff0 + rpf);
            qv1 = *(const bf16x8*)(Vt + voff1 + rpf);
        }
        if (it < 7)
            tilestep(qaA, qpA, it * 7, laccA, o0a, o1a);
        if (it >= d)
            tilestep(qaB, qpB, (it - d) * 7, laccB, o0b, o1b);
        ck0 = pk0; ck1 = pk1; cv0 = pv0; cv1 = pv1;
        pk0 = qk0; pk1 = qk1; pv0 = qv0; pv1 = qv1;
    }

    // l-reduce across the 4 quads; write normalized O^T into At (both tiles)
    laccA += __shfl_xor(laccA, 16);
    laccA += __shfl_xor(laccA, 32);
    laccB += __shfl_xor(laccB, 16);
    laccB += __shfl_xor(laccB, 32);
    const float invA = 1.f / (laccA + 1e-8f);
    const float invB = 1.f / (laccB + 1e-8f);
    {
        const int base = lrow * 264 + h * 32 + quad * 4;
        *(unsigned int*)&At_a[base]          = packbf2(o0a[0] * invA, o0a[1] * invA);
        *(unsigned int*)&At_a[base + 2]      = packbf2(o0a[2] * invA, o0a[3] * invA);
        *(unsigned int*)&At_a[base + 16]     = packbf2(o1a[0] * invA, o1a[1] * invA);
        *(unsigned int*)&At_a[base + 16 + 2] = packbf2(o1a[2] * invA, o1a[3] * invA);
        *(unsigned int*)&At_b[base]          = packbf2(o0b[0] * invB, o0b[1] * invB);
        *(unsigned int*)&At_b[base + 2]      = packbf2(o0b[2] * invB, o0b[3] * invB);
        *(unsigned int*)&At_b[base + 16]     = packbf2(o1b[0] * invB, o1b[1] * invB);
        *(unsigned int*)&At_b[base + 16 + 2] = packbf2(o1b[2] * invB, o1b[3] * invB);
    }
    __syncthreads();

    // ---- oproj: both tiles share each Wofrag fragment ---------------------
    const int T = w >> 2;
    const int ngb = (w & 3) * 2;
    f32x4 accA[2], accB[2];
    accA[0] = zero; accA[1] = zero; accB[0] = zero; accB[1] = zero;

#pragma unroll
    for (int s = 0; s < 8; ++s) {
        bf16x8 bfr[2];
#pragma unroll
        for (int j = 0; j < 2; ++j)
            bfr[j] = *(const bf16x8*)(Wofrag +
                      ((size_t)((T * 8 + s) * 8 + ngb + j) * 64 + L) * 8);
        bf16x8 afA = *(const bf16x8*)(At_a + lrow * 264 + s * 32 + quad * 8);
        bf16x8 afB = *(const bf16x8*)(At_b + lrow * 264 + s * 32 + quad * 8);
#pragma unroll
        for (int j = 0; j < 2; ++j) {
            accA[j] = __builtin_amdgcn_mfma_f32_16x16x32_bf16(afA, bfr[j], accA[j], 0, 0, 0);
            accB[j] = __builtin_amdgcn_mfma_f32_16x16x32_bf16(afB, bfr[j], accB[j], 0, 0, 0);
        }
    }

#pragma unroll
    for (int r = 0; r < 4; ++r) {
        int rowA = pos0a + quad * 4 + r;
        int rowB = pos0b + quad * 4 + r;
#pragma unroll
        for (int j = 0; j < 2; ++j) {
            int c = w * 32 + j * 16 + lrow;
            out[(size_t)rowA * CD + c] = accA[j][r];
            out[(size_t)rowB * CD + c] = accB[j][r];
        }
    }
}

// ---------------------------------------------------------------------------
// Memory plan (ws ~256 MiB; we use ~26 MB):
//   ws[ 0,  8MB): QA bf16 (Q + pe_q)
//   ws[ 8, 16MB): Kd bf16 (QSCALE-folded; tail absorbs Vt underflow reads)
//   ws[16, ~24.02MB): Vt bf16 transposed [ch][VSTR=16416] (8.02 MB)
//   ws[25MB+4KB, +544KB): Wfrag 384KB | pebf 32KB | Wofrag 128KB
// ---------------------------------------------------------------------------
extern "C" void kernel_launch(void* const* d_in, const int* in_sizes, int n_in,
                              void* d_out, int out_size, void* d_ws, size_t ws_size,
                              hipStream_t stream)
{
    const float* x  = (const float*)d_in[0];
    const float* Wq = (const float*)d_in[1];
    const float* Wk = (const float*)d_in[2];
    const float* Wv = (const float*)d_in[3];
    const float* Wo = (const float*)d_in[4];
    const float* pe = (const float*)d_in[5];
    float* out = (float*)d_out;

    char* ws = (char*)d_ws;
    unsigned short* QA = (unsigned short*)ws;
    unsigned short* Kd = (unsigned short*)(ws + (8u << 20));
    unsigned short* Vt = (unsigned short*)(ws + (16u << 20));
    char* fr = ws + (25u << 20) + 4096;
    __hip_bfloat16* Wfrag  = (__hip_bfloat16*)fr;
    __hip_bfloat16* pebf   = (__hip_bfloat16*)(fr + (384u << 10));
    __hip_bfloat16* Wofrag = (__hip_bfloat16*)(fr + (416u << 10));

    convert_kernel<<<136, 256, 0, stream>>>(Wq, Wk, Wv, Wo, pe, Wfrag, pebf, Wofrag);
    qkv_mfma<<<256, 768, 0, stream>>>(x, Wfrag, pe, QA, Kd, Vt);
    attn_oproj<<<512, 512, 0, stream>>>(QA, Kd, Vt, pebf, Wofrag, out);
}

// Round 11
// 113.448 us; speedup vs baseline: 1.4726x; 1.0433x over previous
//
#include <hip/hip_runtime.h>
#include <hip/hip_bf16.h>

// B=4, Y=64, X=64, C=256, H=8, F=32, 7x7 window (S=49). All I/O is FLOAT32.
// NOTE: measured dur_us includes ~55us of harness restore/re-poison
// (256MiB 0xAA fill at ~6TB/s) — kernel-side budget is dur_us - ~55.
static constexpr int NPOS = 4 * 64 * 64;   // 16384 rows
static constexpr int CD   = 256;
// r22: Vt row stride padded 16384 -> 16416 elem (32832B = 513 cache lines):
// exact-32KB stride put all 16 lrow lanes of a bv load in one L1 set.
static constexpr int VSTR = 16416;
#define QSCALE (0.17677669529663687f * 1.4426950408889634f)  // 1/sqrt(32)*log2e

typedef __attribute__((ext_vector_type(8))) short bf16x8;   // MFMA A/B frag
typedef __attribute__((ext_vector_type(4))) float f32x4;    // MFMA C/D frag

__device__ __forceinline__ float bf2f(unsigned short u) {
    return __uint_as_float((unsigned int)u << 16);
}
__device__ __forceinline__ unsigned short bfbits(float f) {
    union { __hip_bfloat16 h; unsigned short u; } cv;
    cv.h = __float2bfloat16(f);
    return cv.u;
}
__device__ __forceinline__ unsigned int packbf2(float lo, float hi) {
    union { __hip_bfloat162 h; unsigned int u; } cv;
    cv.h.x = __float2bfloat16(lo);
    cv.h.y = __float2bfloat16(hi);
    return cv.u;
}
__device__ __forceinline__ uint4 pack8(float4 a, float4 b) {
    uint4 u;
    u.x = packbf2(a.x, a.y); u.y = packbf2(a.z, a.w);
    u.z = packbf2(b.x, b.y); u.w = packbf2(b.z, b.w);
    return u;
}
// gfx950 cross-lane swaps via BUILTINS (VALU pipe; SSA pair results —
// immune to the tied-asm-operand coalescing that zeroed l in r19).
__device__ __forceinline__ void pl32swap(unsigned &a, unsigned &b) {
    auto r = __builtin_amdgcn_permlane32_swap(a, b, false, false);
    a = r[0]; b = r[1];
}
__device__ __forceinline__ void pl16swap(unsigned &a, unsigned &b) {
    auto r = __builtin_amdgcn_permlane16_swap(a, b, false, false);
    a = r[0]; b = r[1];
}

// ---------------------------------------------------------------------------
// convert: Wfrag (Wq|Wk|Wv b-frag bf16, 384KB) + pebf (pe^T b-frag,
// QSCALE-folded, 32KB) + Wofrag (128KB). 136 blocks x 256.  (unchanged)
// ---------------------------------------------------------------------------
__global__ __launch_bounds__(256) void convert_kernel(
    const float* __restrict__ Wq, const float* __restrict__ Wk,
    const float* __restrict__ Wv, const float* __restrict__ Wo,
    const float* __restrict__ pe,
    __hip_bfloat16* __restrict__ Wfrag,
    __hip_bfloat16* __restrict__ pebf,
    __hip_bfloat16* __restrict__ Wofrag)
{
    int t = blockIdx.x * 256 + threadIdx.x;
    if (t < 24576) {
        int L = t & 63, ng = (t >> 6) & 7, s = (t >> 9) & 7, T = t >> 12;
        int mat = T >> 1;
        const float* src = (mat == 0) ? Wq : (mat == 1) ? Wk : Wv;
        int ncol  = (T & 1) * 128 + ng * 16 + (L & 15);
        int kbase = s * 32 + (L >> 4) * 8;
        __hip_bfloat16* dst = Wfrag + ((size_t)((T * 8 + s) * 8 + ng) * 64 + L) * 8;
#pragma unroll
        for (int j = 0; j < 8; ++j)
            dst[j] = __float2bfloat16(src[(kbase + j) * 256 + ncol]);
    } else if (t < 26624) {
        int u = t - 24576;
        int L = u & 63, Tn = (u >> 6) & 3, h = u >> 8;
        int s = Tn * 16 + (L & 15);
        int kbase = (L >> 4) * 8;
        __hip_bfloat16* dst = pebf + ((size_t)((h * 4 + Tn) * 64 + L)) * 8;
#pragma unroll
        for (int j = 0; j < 8; ++j) {
            float v = (s < 49) ? pe[s * 256 + h * 32 + kbase + j] * QSCALE : 0.f;
            dst[j] = __float2bfloat16(v);
        }
    } else if (t < 34816) {
        int u = t - 26624;
        int L = u & 63, ng = (u >> 6) & 7, s = (u >> 9) & 7, T = (u >> 12) & 1;
        int ncol  = T * 128 + ng * 16 + (L & 15);
        int kbase = s * 32 + (L >> 4) * 8;
        __hip_bfloat16* dst = Wofrag + ((size_t)((T * 8 + s) * 8 + ng) * 64 + L) * 8;
#pragma unroll
        for (int j = 0; j < 8; ++j)
            dst[j] = __float2bfloat16(Wo[(kbase + j) * 256 + ncol]);
    }
}

// ---------------------------------------------------------------------------
// Kernel 1 (r21/r22): MERGED QKV GEMM — one 768-thread / 12-wave block per
// 64-row tile computes Q, K, AND V. x staged once (bf16 LDS, stride 264),
// barrier-free MFMA phase, wave w owns weight half T=w>>1, ngb=(w&1)*4.
// Vt stores use padded stride VSTR.  (unchanged)
// ---------------------------------------------------------------------------
__global__ __launch_bounds__(768, 3) void qkv_mfma(
    const float* __restrict__ x,
    const __hip_bfloat16* __restrict__ Wfrag,
    const float* __restrict__ pe,
    unsigned short* __restrict__ QA,
    unsigned short* __restrict__ Kd,
    unsigned short* __restrict__ Vt)
{
    __shared__ __align__(16) unsigned short smem[256 * 68];   // 34.8 KB
    unsigned short* As = smem;                 // x-tile: [64][264] bf16
    const int t = threadIdx.x;                 // 0..767
    const int rowbase = blockIdx.x * 64;
    const int L = t & 63;
    const int w = t >> 6;                      // 0..11
    const int quad = L >> 4, lrow = L & 15;
    const int T = w >> 1;                      // 0..5
    const int ngb = (w & 1) * 4;
    const int g = T >> 1;                      // 0:Q 1:K 2:V
    const int lw = w & 3;                      // wave-within-g (col group)

#pragma unroll
    for (int idx = t; idx < 2048; idx += 768) {
        const int row = idx >> 5, ch8 = idx & 31;
        const float* src = x + (size_t)(rowbase + row) * CD + ch8 * 8;
        float4 f0 = ((const float4*)src)[0];
        float4 f1 = ((const float4*)src)[1];
        *(uint4*)&As[row * 264 + ch8 * 8] = pack8(f0, f1);
    }

    f32x4 acc[4][4];
#pragma unroll
    for (int i = 0; i < 4; ++i)
#pragma unroll
        for (int j = 0; j < 4; ++j) acc[i][j] = (f32x4){0.f, 0.f, 0.f, 0.f};

    const __hip_bfloat16* wbase = Wfrag + ((size_t)(T * 64 + ngb) * 64 + L) * 8;
    bf16x8 bfr[4];
#pragma unroll
    for (int j = 0; j < 4; ++j)
        bfr[j] = *(const bf16x8*)(wbase + (size_t)j * 64 * 8);

    __syncthreads();   // x-tile visible

#pragma unroll
    for (int s = 0; s < 8; ++s) {
        bf16x8 nbfr[4];
        if (s < 7) {
#pragma unroll
            for (int j = 0; j < 4; ++j)
                nbfr[j] = *(const bf16x8*)(wbase + (size_t)((s + 1) * 8 + j) * 64 * 8);
        }
#pragma unroll
        for (int i = 0; i < 4; ++i) {
            bf16x8 af = *(const bf16x8*)&As[(i * 16 + lrow) * 264 + s * 32 + quad * 8];
#pragma unroll
            for (int j = 0; j < 4; ++j)
                acc[i][j] = __builtin_amdgcn_mfma_f32_16x16x32_bf16(af, bfr[j], acc[i][j], 0, 0, 0);
        }
#pragma unroll
        for (int j = 0; j < 4; ++j) bfr[j] = nbfr[j];
    }

    __syncthreads();   // all x-tile reads done; smem may be reused by V

    if (g == 0) {
#pragma unroll
        for (int i = 0; i < 4; ++i)
#pragma unroll
            for (int r = 0; r < 4; ++r) {
                int row = rowbase + i * 16 + quad * 4 + r;
                int yy = (row >> 6) & 63, xx = row & 63;
                int cy = min(max(yy, 3), 60), cx = min(max(xx, 3), 60);
                int qidx = (yy - cy + 3) * 7 + (xx - cx + 3);
#pragma unroll
                for (int j = 0; j < 4; ++j) {
                    int c = lw * 64 + j * 16 + lrow;
                    QA[(size_t)row * CD + c] = bfbits(acc[i][j][r] + pe[qidx * 256 + c]);
                }
            }
    } else if (g == 1) {
#pragma unroll
        for (int i = 0; i < 4; ++i)
#pragma unroll
            for (int r = 0; r < 4; ++r) {
                int row = rowbase + i * 16 + quad * 4 + r;
#pragma unroll
                for (int j = 0; j < 4; ++j) {
                    int c = lw * 64 + j * 16 + lrow;
                    Kd[(size_t)row * CD + c] = bfbits(acc[i][j][r] * QSCALE);
                }
            }
    } else {
        unsigned short* vt = smem;   // [256 ch][68] bf16 (17408 shorts)
#pragma unroll
        for (int i = 0; i < 4; ++i)
#pragma unroll
            for (int j = 0; j < 4; ++j) {
                int c = lw * 64 + j * 16 + lrow;
                int row0 = i * 16 + quad * 4;
                *(unsigned int*)&vt[c * 68 + row0] =
                    (unsigned int)bfbits(acc[i][j][0]) | ((unsigned int)bfbits(acc[i][j][1]) << 16);
                *(unsigned int*)&vt[c * 68 + row0 + 2] =
                    (unsigned int)bfbits(acc[i][j][2]) | ((unsigned int)bfbits(acc[i][j][3]) << 16);
            }
    }
    __syncthreads();   // vt complete (uniform barrier — no barrier in branches)

    if (g == 2) {      // waves 8..11 (256 threads) stream vt -> Vt coalesced
        const int t4 = t - 512;
        const int grp = t4 >> 4, lig = t4 & 15;
        const int row_off = lig * 4;
        unsigned short* vt = smem;
#pragma unroll
        for (int pass = 0; pass < 16; ++pass) {
            int c = pass * 16 + grp;
            *(ushort4*)(Vt + (size_t)c * VSTR + rowbase + row_off) =
                *(const ushort4*)&vt[c * 68 + row_off];
        }
    }
}

// ---------------------------------------------------------------------------
// Kernel 2 (r28 = r23 REVERT + setprio): paired-tile attention + oproj,
// depth-1 prefetch (the proven 114.6us equilibrium). Structural sweep
// r24-r27 falsified: y-quad (÷2 occ, neutral), LDS staging (+barriers,
// regressed), depth-2 (÷1.5 occ, regressed even unspilled). This shape
// balances per-wave latency coverage against TLP; any trade that spends
// occupancy or adds sync loses. NEW vs r23: T5 s_setprio(1) around the
// MFMA/exp body only — zero register cost, barrier-free multi-wave regime
// where it measured +4-7% on attn (m191); never tested standalone (r26
// bundled it with the fatal spill). Numerics bit-identical.
// ---------------------------------------------------------------------------
__global__ __launch_bounds__(512, 4) void attn_oproj(
    const unsigned short* __restrict__ QA,   // bf16 [pos][256] (Q + pe_q)
    const unsigned short* __restrict__ Kd,
    const unsigned short* __restrict__ Vt,
    const __hip_bfloat16* __restrict__ pebf,
    const __hip_bfloat16* __restrict__ Wofrag,
    float* __restrict__ out)
{
    __shared__ __align__(16) unsigned short qpes[8 * 2 * 1152];  // 36 KB
    __shared__ __align__(16) unsigned short At[2 * 16 * 264];    // 16.9 KB
    const int t = threadIdx.x, w = t >> 6, L = t & 63;
    const int lrow = L & 15, quad = L >> 4;
    const int bid = blockIdx.x;
    const int p = ((bid & 7) << 6) | (bid >> 3);   // XCD-local y-band
    const int b = p >> 7, ypair = (p >> 2) & 31, x0 = (p & 3) * 16;
    const int yyA = ypair * 2;
    const int pos0a = b * 4096 + yyA * 64 + x0;
    const int pos0b = pos0a + 64;
    const int cyA = min(max(yyA, 3), 60);
    const int cyB = min(max(yyA + 1, 3), 60);
    const int d = cyB - cyA;                  // 0 or 1
    const int nit = 7 + d;                    // 7 or 8 shared K/V rows
    const int h = w;

    const int kc0 = min(max(x0 - 8 + lrow, 0), 63);
    const int kc1 = min(max(x0 + 8 + lrow, 0), 63);
    const f32x4 zero = {0.f, 0.f, 0.f, 0.f};
    unsigned short* qpA = qpes + w * 2304;
    unsigned short* qpB = qpA + 1152;
    unsigned short* At_a = At;
    unsigned short* At_b = At + 16 * 264;

    // x-geometry (shared by both tiles): lane's q-row is lrow; key slots
    // quad*4+r (s0) and 16+quad*4+r (s1).
    const int cx = min(max(x0 + lrow, 3), 60) - x0 + 5;
    int qiA[4], qiB[4];
    float mkA[4], mkB[4];
#pragma unroll
    for (int r = 0; r < 4; ++r) {
        const int sl = quad * 4 + r;
        int dxa = sl - cx;
        qiA[r] = lrow * 72 + min(max(dxa, 0), 6);
        mkA[r] = ((unsigned)dxa <= 6u) ? 1.f : 0.f;
        int dxb = 16 + sl - cx;
        qiB[r] = lrow * 72 + min(max(dxb, 0), 6);
        mkB[r] = ((unsigned)dxb <= 6u) ? 1.f : 0.f;
    }

    const bf16x8 qaA = *(const bf16x8*)(QA + (size_t)(pos0a + lrow) * 256 + h * 32 + quad * 8);
    const bf16x8 qaB = *(const bf16x8*)(QA + (size_t)(pos0b + lrow) * 256 + h * 32 + quad * 8);

    // QpeT for both tiles (pe b-frag loaded once per Tn)
#pragma unroll
    for (int Tn = 0; Tn < 4; ++Tn) {
        bf16x8 bp = *(const bf16x8*)(pebf + ((size_t)((h * 4 + Tn) * 64 + L)) * 8);
        f32x4 cA = __builtin_amdgcn_mfma_f32_16x16x32_bf16(bp, qaA, zero, 0, 0, 0);
        f32x4 cB = __builtin_amdgcn_mfma_f32_16x16x32_bf16(bp, qaB, zero, 0, 0, 0);
        *(unsigned int*)&qpA[lrow * 72 + Tn * 16 + quad * 4]     = packbf2(cA[0], cA[1]);
        *(unsigned int*)&qpA[lrow * 72 + Tn * 16 + quad * 4 + 2] = packbf2(cA[2], cA[3]);
        *(unsigned int*)&qpB[lrow * 72 + Tn * 16 + quad * 4]     = packbf2(cB[0], cB[1]);
        *(unsigned int*)&qpB[lrow * 72 + Tn * 16 + quad * 4 + 2] = packbf2(cB[2], cB[3]);
    }
    __builtin_amdgcn_s_waitcnt(0xc07f);   // lgkmcnt(0): qp visible to own wave

    float laccA = 0.f, laccB = 0.f;
    f32x4 o0a = zero, o1a = zero, o0b = zero, o1b = zero;
    int rowpos = b * 4096 + (cyA - 3) * 64;

    const size_t koff = h * 32 + quad * 8;
    const size_t voff0 = (size_t)(h * 32 + lrow) * VSTR + x0 - 8 + quad * 8;
    const size_t voff1 = (size_t)(h * 32 + 16 + lrow) * VSTR + x0 - 8 + quad * 8;
    bf16x8 bk0 = *(const bf16x8*)(Kd + (size_t)(rowpos + kc0) * 256 + koff);
    bf16x8 bk1 = *(const bf16x8*)(Kd + (size_t)(rowpos + kc1) * 256 + koff);
    bf16x8 bv0 = *(const bf16x8*)(Vt + voff0 + rowpos);
    bf16x8 bv1 = *(const bf16x8*)(Vt + voff1 + rowpos);

    // one tile's QK->softmax->PV step on the current (bk,bv) row
    auto tilestep = [&](const bf16x8& qa_, const unsigned short* qp_, int qpofs,
                        float& lacc_, f32x4& o0_, f32x4& o1_) {
        f32x4 s0 = __builtin_amdgcn_mfma_f32_16x16x32_bf16(bk0, qa_, zero, 0, 0, 0);
        f32x4 s1 = __builtin_amdgcn_mfma_f32_16x16x32_bf16(bk1, qa_, zero, 0, 0, 0);
        float e00 = exp2f(s0[0] + bf2f(qp_[qiA[0] + qpofs])) * mkA[0];
        float e01 = exp2f(s0[1] + bf2f(qp_[qiA[1] + qpofs])) * mkA[1];
        float e02 = exp2f(s0[2] + bf2f(qp_[qiA[2] + qpofs])) * mkA[2];
        float e03 = exp2f(s0[3] + bf2f(qp_[qiA[3] + qpofs])) * mkA[3];
        float e10 = exp2f(s1[0] + bf2f(qp_[qiB[0] + qpofs])) * mkB[0];
        float e11 = exp2f(s1[1] + bf2f(qp_[qiB[1] + qpofs])) * mkB[1];
        float e12 = exp2f(s1[2] + bf2f(qp_[qiB[2] + qpofs])) * mkB[2];
        float e13 = exp2f(s1[3] + bf2f(qp_[qiB[3] + qpofs])) * mkB[3];
        lacc_ += ((e00 + e01) + (e02 + e03)) + ((e10 + e11) + (e12 + e13));
        unsigned p0 = packbf2(e00, e01), p1 = packbf2(e02, e03);
        unsigned z0 = packbf2(e10, e11), z1 = packbf2(e12, e13);
        pl32swap(p0, z0); pl16swap(p0, z0);
        pl32swap(p1, z1); pl16swap(p1, z1);
        union { unsigned u[4]; bf16x8 v; } pb;
        pb.u[0] = p0; pb.u[1] = p1; pb.u[2] = z0; pb.u[3] = z1;
        o0_ = __builtin_amdgcn_mfma_f32_16x16x32_bf16(bv0, pb.v, o0_, 0, 0, 0);
        o1_ = __builtin_amdgcn_mfma_f32_16x16x32_bf16(bv1, pb.v, o1_, 0, 0, 0);
    };

    for (int i = 0; i < nit; ++i) {
        const int rnext = rowpos + 64;
        bf16x8 nk0, nk1, nv0, nv1;
        if (i < nit - 1) {                 // next-row loads in flight
            nk0 = *(const bf16x8*)(Kd + (size_t)(rnext + kc0) * 256 + koff);
            nk1 = *(const bf16x8*)(Kd + (size_t)(rnext + kc1) * 256 + koff);
            nv0 = *(const bf16x8*)(Vt + voff0 + rnext);
            nv1 = *(const bf16x8*)(Vt + voff1 + rnext);
        }
        __builtin_amdgcn_s_setprio(1);     // favor MFMA/exp body (T5)
        if (i < 7)                          // tile A: dy = i
            tilestep(qaA, qpA, i * 7, laccA, o0a, o1a);
        if (i >= d)                         // tile B: dy = i - d
            tilestep(qaB, qpB, (i - d) * 7, laccB, o0b, o1b);
        __builtin_amdgcn_s_setprio(0);
        bk0 = nk0; bk1 = nk1; bv0 = nv0; bv1 = nv1;
        rowpos = rnext;
    }

    // l-reduce across the 4 quads; write normalized O^T into At (both tiles)
    laccA += __shfl_xor(laccA, 16);
    laccA += __shfl_xor(laccA, 32);
    laccB += __shfl_xor(laccB, 16);
    laccB += __shfl_xor(laccB, 32);
    const float invA = 1.f / (laccA + 1e-8f);
    const float invB = 1.f / (laccB + 1e-8f);
    {
        const int base = lrow * 264 + h * 32 + quad * 4;
        *(unsigned int*)&At_a[base]          = packbf2(o0a[0] * invA, o0a[1] * invA);
        *(unsigned int*)&At_a[base + 2]      = packbf2(o0a[2] * invA, o0a[3] * invA);
        *(unsigned int*)&At_a[base + 16]     = packbf2(o1a[0] * invA, o1a[1] * invA);
        *(unsigned int*)&At_a[base + 16 + 2] = packbf2(o1a[2] * invA, o1a[3] * invA);
        *(unsigned int*)&At_b[base]          = packbf2(o0b[0] * invB, o0b[1] * invB);
        *(unsigned int*)&At_b[base + 2]      = packbf2(o0b[2] * invB, o0b[3] * invB);
        *(unsigned int*)&At_b[base + 16]     = packbf2(o1b[0] * invB, o1b[1] * invB);
        *(unsigned int*)&At_b[base + 16 + 2] = packbf2(o1b[2] * invB, o1b[3] * invB);
    }
    __syncthreads();

    // ---- oproj: both tiles share each Wofrag fragment ---------------------
    const int T = w >> 2;
    const int ngb = (w & 3) * 2;
    f32x4 accA[2], accB[2];
    accA[0] = zero; accA[1] = zero; accB[0] = zero; accB[1] = zero;

#pragma unroll
    for (int s = 0; s < 8; ++s) {
        bf16x8 bfr[2];
#pragma unroll
        for (int j = 0; j < 2; ++j)
            bfr[j] = *(const bf16x8*)(Wofrag +
                      ((size_t)((T * 8 + s) * 8 + ngb + j) * 64 + L) * 8);
        bf16x8 afA = *(const bf16x8*)(At_a + lrow * 264 + s * 32 + quad * 8);
        bf16x8 afB = *(const bf16x8*)(At_b + lrow * 264 + s * 32 + quad * 8);
#pragma unroll
        for (int j = 0; j < 2; ++j) {
            accA[j] = __builtin_amdgcn_mfma_f32_16x16x32_bf16(afA, bfr[j], accA[j], 0, 0, 0);
            accB[j] = __builtin_amdgcn_mfma_f32_16x16x32_bf16(afB, bfr[j], accB[j], 0, 0, 0);
        }
    }

#pragma unroll
    for (int r = 0; r < 4; ++r) {
        int rowA = pos0a + quad * 4 + r;
        int rowB = pos0b + quad * 4 + r;
#pragma unroll
        for (int j = 0; j < 2; ++j) {
            int c = w * 32 + j * 16 + lrow;
            out[(size_t)rowA * CD + c] = accA[j][r];
            out[(size_t)rowB * CD + c] = accB[j][r];
        }
    }
}

// ---------------------------------------------------------------------------
// Memory plan (ws ~256 MiB; we use ~26 MB):
//   ws[ 0,  8MB): QA bf16 (Q + pe_q)
//   ws[ 8, 16MB): Kd bf16 (QSCALE-folded; tail absorbs Vt underflow reads)
//   ws[16, ~24.02MB): Vt bf16 transposed [ch][VSTR=16416] (8.02 MB)
//   ws[25MB+4KB, +544KB): Wfrag 384KB | pebf 32KB | Wofrag 128KB
// ---------------------------------------------------------------------------
extern "C" void kernel_launch(void* const* d_in, const int* in_sizes, int n_in,
                              void* d_out, int out_size, void* d_ws, size_t ws_size,
                              hipStream_t stream)
{
    const float* x  = (const float*)d_in[0];
    const float* Wq = (const float*)d_in[1];
    const float* Wk = (const float*)d_in[2];
    const float* Wv = (const float*)d_in[3];
    const float* Wo = (const float*)d_in[4];
    const float* pe = (const float*)d_in[5];
    float* out = (float*)d_out;

    char* ws = (char*)d_ws;
    unsigned short* QA = (unsigned short*)ws;
    unsigned short* Kd = (unsigned short*)(ws + (8u << 20));
    unsigned short* Vt = (unsigned short*)(ws + (16u << 20));
    char* fr = ws + (25u << 20) + 4096;
    __hip_bfloat16* Wfrag  = (__hip_bfloat16*)fr;
    __hip_bfloat16* pebf   = (__hip_bfloat16*)(fr + (384u << 10));
    __hip_bfloat16* Wofrag = (__hip_bfloat16*)(fr + (416u << 10));

    convert_kernel<<<136, 256, 0, stream>>>(Wq, Wk, Wv, Wo, pe, Wfrag, pebf, Wofrag);
    qkv_mfma<<<256, 768, 0, stream>>>(x, Wfrag, pe, QA, Kd, Vt);
    attn_oproj<<<512, 512, 0, stream>>>(QA, Kd, Vt, pebf, Wofrag, out);
}